// Round 1
// baseline (306.529 us; speedup 1.0000x reference)
//
#include <hip/hip_runtime.h>
#include <hip/hip_bf16.h>

// BinCat: out[b,i,:] = cats[idx(b,i),:] where
// idx = sum_j (1 - x[b,i,j]) << (19 - j).
// B=4096, I=16, L=20, D=64. Pure gather; memory-bound.

#define BATCH 4096
#define I_DIM 16
#define LENGTH 20
#define DIM 64

#define ROWS (BATCH * I_DIM)          // 65536
#define ROWS_PER_BLOCK 16
#define THREADS 256

__global__ __launch_bounds__(THREADS) void bincat_gather(
    const int* __restrict__ x,      // (ROWS, LENGTH)
    const float* __restrict__ cats, // (2^20, DIM)
    float* __restrict__ out)        // (ROWS, DIM)
{
    __shared__ int sbits[ROWS_PER_BLOCK * LENGTH]; // 320 ints
    __shared__ int sidx[ROWS_PER_BLOCK];

    const int t = threadIdx.x;
    const int row0 = blockIdx.x * ROWS_PER_BLOCK;

    // Stage this block's x bits: 320 contiguous ints, coalesced.
    const int base = row0 * LENGTH;
    for (int i = t; i < ROWS_PER_BLOCK * LENGTH; i += THREADS) {
        sbits[i] = x[base + i];
    }
    __syncthreads();

    // Threads 0..15 each fold one row's 20 bits into an index.
    if (t < ROWS_PER_BLOCK) {
        int idx = 0;
        #pragma unroll
        for (int j = 0; j < LENGTH; ++j) {
            idx += (1 - sbits[t * LENGTH + j]) << (LENGTH - 1 - j);
        }
        sidx[t] = idx;
    }
    __syncthreads();

    // Copy: 16 threads per row, float4 each -> 256 B/row.
    const int row = t >> 4;   // 0..15
    const int pos = t & 15;   // 0..15
    const int idx = sidx[row];

    const float4* __restrict__ src =
        (const float4*)(cats + (size_t)idx * DIM);
    float4 v = src[pos];

    float4* __restrict__ dst =
        (float4*)(out + (size_t)(row0 + row) * DIM);
    dst[pos] = v;
}

extern "C" void kernel_launch(void* const* d_in, const int* in_sizes, int n_in,
                              void* d_out, int out_size, void* d_ws, size_t ws_size,
                              hipStream_t stream) {
    const int* x = (const int*)d_in[0];       // (4096,16,20) int32
    const float* cats = (const float*)d_in[1]; // (2^20, 64) fp32
    float* out = (float*)d_out;                // (4096,16,64) fp32

    dim3 grid(ROWS / ROWS_PER_BLOCK); // 4096 blocks
    dim3 block(THREADS);
    bincat_gather<<<grid, block, 0, stream>>>(x, cats, out);
}